// Round 5
// baseline (588.313 us; speedup 1.0000x reference)
//
#include <hip/hip_runtime.h>

// SSM4D: causal depthwise conv1d, B=16, C=1024, T=3000, K=24, fp32.
// y[b,c,t] = sum_{d=0..23} w[c][d] * x[b,c,t-d],  w[c][d] = kern[c][K-1-d]
//
// R7: latency theory. R2/R3/R6 (49152 micro-blocks, 1 tile/thread) all pin at
// conv~120us with EVERY pipe <55% (2.5TB/s, VALUBusy 31%, occ 53%): each block
// is a ~5us serial latency chain (launch -> weights -> 7 loads -> compute ->
// store) and the CU only holds 8 blocks -> 192 blocks/CU x ~0.6us = ~120us.
// Now: 1024 long-lived blocks (exactly 4/CU, one batch, no tail), each streams
// 16 rows x 3 tiles with an explicit register double-buffer pipeline: tile i+1
// loads issued before tile i FMAs. Weights for all 16 rows preloaded once to
// LDS (1.5KB, uniform-addr broadcast reads). All win[] indices are static
// after unroll (no scratch). R4's failure mode (serial tile loop, VGPR=40,
// zero overlap) is exactly what the explicit A/B buffers prevent.
// Roofline: FETCH ~100MB + WRITE ~194MB -> ~48us @ 6.3 TB/s.

#define KSZ   24
#define T_LEN 3000
#define C_CH  1024
#define B_N   16
#define OPT   4                    // outputs per thread per tile (one float4)
#define TPB   256
#define TILE  (TPB * OPT)          // 1024
#define RPB   16                   // rows per block
#define NBLK  ((B_N * C_CH) / RPB) // 1024 blocks = 4 per CU

typedef float f32x4 __attribute__((ext_vector_type(4)));

__device__ __forceinline__ float cos_approx(float v) {
    float v2 = v * v;
    return 1.0f - 0.5f * v2 + (v2 * v2) * (1.0f / 24.0f);
}

__global__ void ssm4d_weights(const float* __restrict__ alpha,
                              const float* __restrict__ beta,
                              const float* __restrict__ theta,
                              float* __restrict__ w) {
    const int i = blockIdx.x * blockDim.x + threadIdx.x;   // i = c*24 + d
    if (i >= C_CH * KSZ) return;
    const int c = i / KSZ;
    const int d = i - c * KSZ;
    const int k = (KSZ - 1) - d;                           // flip for causal FIR
    const float a   = fmaxf(alpha[c], 1e-6f);
    const float dec = expf(logf(a) * (float)k);
    w[i] = beta[c] * dec * cos_approx(theta[c] * (float)k);
}

// win[p] = xr[t - 24 + p], p = 0..27; zero outside [0, T_LEN)
__device__ __forceinline__ void loadwin(float win[KSZ + OPT],
                                        const float* __restrict__ xr, int t) {
    if (t >= KSZ && t + OPT <= T_LEN) {          // interior: 7 coalesced float4
        const float4* xp = (const float4*)(xr + t - KSZ);
#pragma unroll
        for (int q = 0; q < (KSZ + OPT) / 4; ++q) {
            float4 v = xp[q];
            win[4 * q + 0] = v.x; win[4 * q + 1] = v.y;
            win[4 * q + 2] = v.z; win[4 * q + 3] = v.w;
        }
    } else {                                     // head pad / inactive tail
#pragma unroll
        for (int p = 0; p < KSZ + OPT; ++p) {
            const int idx = t - KSZ + p;
            // t<T_LEN guard also keeps tail threads (t>=3000) from OOB reads
            win[p] = (t < T_LEN && idx >= 0) ? xr[idx] : 0.0f;
        }
    }
}

__device__ __forceinline__ void compute_store(const float win[KSZ + OPT],
                                              const float* ws_row,   // LDS
                                              float* __restrict__ yr, int t) {
    float wr[KSZ];
#pragma unroll
    for (int q = 0; q < KSZ / 4; ++q) {          // uniform-addr ds_read: broadcast
        f32x4 v = *(const f32x4*)(ws_row + 4 * q);
        wr[4 * q + 0] = v.x; wr[4 * q + 1] = v.y;
        wr[4 * q + 2] = v.z; wr[4 * q + 3] = v.w;
    }
    float acc[OPT];
#pragma unroll
    for (int m = 0; m < OPT; ++m) acc[m] = 0.0f;
#pragma unroll
    for (int d = 0; d < KSZ; ++d) {
#pragma unroll
        for (int m = 0; m < OPT; ++m)
            acc[m] = fmaf(wr[d], win[KSZ + m - d], acc[m]);
    }
    if (t < T_LEN) {
        f32x4 out = { acc[0], acc[1], acc[2], acc[3] };
        __builtin_nontemporal_store(out, (f32x4*)(yr + t));  // y never re-read
    }
}

__global__ __launch_bounds__(TPB, 4) void ssm4d_conv(
        const float* __restrict__ x,
        const float* __restrict__ w,
        float* __restrict__ y) {
    const int row0 = blockIdx.x * RPB;
    const float* xb = x + (long)row0 * T_LEN;
    float*       yb = y + (long)row0 * T_LEN;
    const int tid4  = (int)threadIdx.x * OPT;

    // all 16 rows' weights -> LDS once (96 threads x one float4)
    __shared__ float ws[RPB][KSZ];
    if (threadIdx.x < RPB * (KSZ / 4)) {
        const int r = threadIdx.x / (KSZ / 4);
        const int q = threadIdx.x % (KSZ / 4);
        const int c = (row0 + r) & (C_CH - 1);
        *(float4*)&ws[r][4 * q] = *(const float4*)(w + c * KSZ + 4 * q);
    }
    __syncthreads();

    float winA[KSZ + OPT], winB[KSZ + OPT];

    loadwin(winA, xb, 0 * TILE + tid4);                    // (r=0, tx=0)

#pragma unroll 1
    for (int it = 0; it < RPB / 2; ++it) {                 // 2 rows per iter
        const int r0 = 2 * it;
        const float* x0 = xb + (long)r0 * T_LEN;
        const float* x1 = x0 + T_LEN;
        float* y0 = yb + (long)r0 * T_LEN;
        float* y1 = y0 + T_LEN;

        // prefetch next tile into the other buffer, then consume current
        loadwin(winB, x0, 1 * TILE + tid4);
        compute_store(winA, ws[r0],     y0, 0 * TILE + tid4);
        loadwin(winA, x0, 2 * TILE + tid4);
        compute_store(winB, ws[r0],     y0, 1 * TILE + tid4);
        loadwin(winB, x1, 0 * TILE + tid4);
        compute_store(winA, ws[r0],     y0, 2 * TILE + tid4);
        loadwin(winA, x1, 1 * TILE + tid4);
        compute_store(winB, ws[r0 + 1], y1, 0 * TILE + tid4);
        loadwin(winB, x1, 2 * TILE + tid4);
        compute_store(winA, ws[r0 + 1], y1, 1 * TILE + tid4);
        if (it < RPB / 2 - 1)
            loadwin(winA, x1 + T_LEN, 0 * TILE + tid4);    // next iter (r0+2, tx=0)
        compute_store(winB, ws[r0 + 1], y1, 2 * TILE + tid4);
    }
}

extern "C" void kernel_launch(void* const* d_in, const int* in_sizes, int n_in,
                              void* d_out, int out_size, void* d_ws, size_t ws_size,
                              hipStream_t stream) {
    const float* x     = (const float*)d_in[0];
    const float* alpha = (const float*)d_in[1];
    const float* beta  = (const float*)d_in[2];
    const float* theta = (const float*)d_in[3];
    float* y = (float*)d_out;
    float* w = (float*)d_ws;                     // 1024*24 floats = 96 KB

    ssm4d_weights<<<(C_CH * KSZ + 255) / 256, 256, 0, stream>>>(alpha, beta, theta, w);
    ssm4d_conv<<<NBLK, TPB, 0, stream>>>(x, w, y);
}

// Round 6
// 328.058 us; speedup vs baseline: 1.7933x; 1.7933x over previous
//
#include <hip/hip_runtime.h>

// SSM4D: causal depthwise conv1d, B=16, C=1024, T=3000, K=24, fp32.
// y[b,c,t] = sum_{d=0..23} w[c][d] * x[b,c,t-d],  w[c][d] = kern[c][K-1-d]
//
// R8: read-once LDS row staging. R6's 120us conv decomposed as ~36us L1/TA
// (7 overlapping window loads/thread = 6.4x amplification) + ~37us VALU +
// ~48us HBM, none >55% busy. This kernel removes the L1 slice: one block per
// row; each thread loads 3 DISJOINT coalesced float4 chunks (row fetched
// exactly once), staged to LDS with:
//   - 6-chunk zero front pad (causal boundary handled with zero branches)
//   - +1-chunk-per-8 padding pos(L)=L+(L>>3): the stride-16B ds_read_b128
//     window reads would be 8-way bank conflicts (R1's killer); padded they
//     are <=2-way, which is free (m136).
// Weights computed in-block BETWEEN global-load issue and LDS write (hidden
// under load latency). Regular stores (R7: nt stores under temporal spread
// tripled WRITE_SIZE to 567MB — falsified). No pre-kernel, no workspace.
// Roofline: ~100-197MB fetch + ~194MB write -> 47-62us @ 6.3 TB/s.

#define KSZ   24
#define T_LEN 3000
#define C_CH  1024
#define B_N   16
#define TPB   256
#define OPT   4
#define TILE  (TPB * OPT)          // 1024
#define CHK   (T_LEN / 4)          // 750 float4 chunks per row
#define PADC  (KSZ / 4)            // 6 front zero-pad chunks
#define LMAX  (CHK + PADC - 1)     // 755 = max logical chunk index
#define PPOS(L) ((L) + ((L) >> 3)) // bank-conflict padding
#define LDSN  (PPOS(LMAX) + 1)     // 850 physical chunks = 13.6 KB

typedef float f32x4 __attribute__((ext_vector_type(4)));

__device__ __forceinline__ float cos_approx(float v) {
    float v2 = v * v;
    return 1.0f - 0.5f * v2 + (v2 * v2) * (1.0f / 24.0f);
}

__global__ __launch_bounds__(TPB) void ssm4d_conv(
        const float* __restrict__ x,
        const float* __restrict__ alpha,
        const float* __restrict__ beta,
        const float* __restrict__ theta,
        float* __restrict__ y) {
    const int row   = blockIdx.x;            // b*C + c
    const int c     = row & (C_CH - 1);
    const long base = (long)row * T_LEN;
    const int tid   = threadIdx.x;

    __shared__ float ws[KSZ];
    __shared__ f32x4 lds[LDSN];

    // 1) issue the row's global loads: 3 disjoint coalesced chunks per thread
    const f32x4* xp = (const f32x4*)(x + base);      // row*12000B: 16B aligned
    const int c0 = tid, c1 = tid + TPB, c2 = tid + 2 * TPB;
    f32x4 a0 = xp[c0];
    f32x4 a1 = xp[c1];
    f32x4 a2 = (c2 < CHK) ? xp[c2] : (f32x4){0.f, 0.f, 0.f, 0.f};

    // 2) weights + zero pad while loads are in flight (same formula as prior
    //    passing kernels, bit-identical)
    if (tid < KSZ) {
        const int k = (KSZ - 1) - tid;               // flip for causal FIR
        const float a   = fmaxf(alpha[c], 1e-6f);
        const float dec = expf(logf(a) * (float)k);
        ws[tid] = beta[c] * dec * cos_approx(theta[c] * (float)k);
    }
    if (tid < PADC) lds[tid] = (f32x4){0.f, 0.f, 0.f, 0.f};  // PPOS(L)=L for L<8

    // 3) stage to LDS (padded positions; logical chunk = x chunk + PADC)
    lds[PPOS(c0 + PADC)] = a0;
    lds[PPOS(c1 + PADC)] = a1;
    if (c2 < CHK) lds[PPOS(c2 + PADC)] = a2;
    __syncthreads();

    // 4) weights to regs: uniform-address LDS reads = broadcast, conflict-free
    float wr[KSZ];
#pragma unroll
    for (int d = 0; d < KSZ; ++d) wr[d] = ws[d];

    // 5) three tiles from LDS
#pragma unroll
    for (int s = 0; s < 3; ++s) {
        const int t = s * TILE + tid * OPT;          // first output
        if (t < T_LEN) {                             // tail of tile 2 idle
            // win[p] = x[t-24+p]; logical chunk L = s*256 + tid + q
            float win[KSZ + OPT];
            const int L0 = s * (TILE / 4) + tid;
#pragma unroll
            for (int q = 0; q < (KSZ + OPT) / 4; ++q) {
                f32x4 v = lds[PPOS(L0 + q)];
                win[4 * q + 0] = v.x; win[4 * q + 1] = v.y;
                win[4 * q + 2] = v.z; win[4 * q + 3] = v.w;
            }
            float acc[OPT];
#pragma unroll
            for (int m = 0; m < OPT; ++m) acc[m] = 0.0f;
#pragma unroll
            for (int d = 0; d < KSZ; ++d) {
#pragma unroll
                for (int m = 0; m < OPT; ++m)
                    acc[m] = fmaf(wr[d], win[KSZ + m - d], acc[m]);
            }
            *(float4*)(y + base + t) = make_float4(acc[0], acc[1], acc[2], acc[3]);
        }
    }
}

extern "C" void kernel_launch(void* const* d_in, const int* in_sizes, int n_in,
                              void* d_out, int out_size, void* d_ws, size_t ws_size,
                              hipStream_t stream) {
    const float* x     = (const float*)d_in[0];
    const float* alpha = (const float*)d_in[1];
    const float* beta  = (const float*)d_in[2];
    const float* theta = (const float*)d_in[3];
    float* y = (float*)d_out;

    ssm4d_conv<<<B_N * C_CH, TPB, 0, stream>>>(x, alpha, beta, theta, y);
}